// Round 2
// baseline (4508.281 us; speedup 1.0000x reference)
//
#include <hip/hip_runtime.h>
#include <hip/hip_bf16.h>
#include <math.h>

// Problem constants (B=2, S=2048, D=1024, H=16, DH=64)
#define BB 2
#define SS 2048
#define DD 1024
#define HH 16
#define DH 64
#define NTOK (BB * SS)   // 4096
#define LN_EPS 1e-5f

// ---------------------------------------------------------------------------
// LayerNorm: one block per token row (D=1024), 256 threads, 4 elems/thread.
// Two-pass (centered) to match reference numerics.
// ---------------------------------------------------------------------------
__global__ __launch_bounds__(256) void ln_kernel(const float* __restrict__ x,
                                                 const float* __restrict__ gamma,
                                                 const float* __restrict__ beta,
                                                 float* __restrict__ out) {
    const int row = blockIdx.x;
    const int tid = threadIdx.x;
    __shared__ float red[256];

    const float* xp = x + (size_t)row * DD;
    float vals[4];
    float s = 0.f;
#pragma unroll
    for (int i = 0; i < 4; ++i) {
        float v = xp[tid + i * 256];
        vals[i] = v;
        s += v;
    }
    red[tid] = s;
    __syncthreads();
    for (int st = 128; st > 0; st >>= 1) {
        if (tid < st) red[tid] += red[tid + st];
        __syncthreads();
    }
    const float mu = red[0] * (1.0f / DD);
    __syncthreads();

    float sq = 0.f;
#pragma unroll
    for (int i = 0; i < 4; ++i) {
        float d = vals[i] - mu;
        sq += d * d;
    }
    red[tid] = sq;
    __syncthreads();
    for (int st = 128; st > 0; st >>= 1) {
        if (tid < st) red[tid] += red[tid + st];
        __syncthreads();
    }
    const float var = red[0] * (1.0f / DD);
    const float rinv = rsqrtf(var + LN_EPS);

    float* op = out + (size_t)row * DD;
#pragma unroll
    for (int i = 0; i < 4; ++i) {
        int j = tid + i * 256;
        op[j] = gamma[j] * ((vals[i] - mu) * rinv) + beta[j];
    }
}

// ---------------------------------------------------------------------------
// Tiled fp32 GEMM: C[M,N] = A[M,K] @ W[K,N] (+ optional fp32 residual).
// 64x64 tile, 256 threads, 4x4 micro-tile, K-step 16.
// ---------------------------------------------------------------------------
template <int RES>
__global__ __launch_bounds__(256) void gemm_kernel(const float* __restrict__ A,
                                                   const float* __restrict__ W,
                                                   const float* __restrict__ res,
                                                   float* __restrict__ C,
                                                   int M, int N, int K) {
    __shared__ float As[16][68];  // [k][row]
    __shared__ float Ws[16][68];  // [k][col]

    const int tx = threadIdx.x;  // 0..15 -> cols
    const int ty = threadIdx.y;  // 0..15 -> rows
    const int tid = ty * 16 + tx;
    const int row0 = blockIdx.y * 64;
    const int colb = blockIdx.x * 64;

    float acc[4][4] = {};

    for (int k0 = 0; k0 < K; k0 += 16) {
        // Stage A tile 64x16: each thread one float4 along K
        {
            int e = tid * 4;
            int r = e >> 4;
            int c = e & 15;
            const float4 av = *(const float4*)(&A[(size_t)(row0 + r) * K + k0 + c]);
            As[c + 0][r] = av.x;
            As[c + 1][r] = av.y;
            As[c + 2][r] = av.z;
            As[c + 3][r] = av.w;
        }
        // Stage W tile 16x64: each thread one float4 along N
        {
            int e = tid * 4;
            int kk = e >> 6;
            int c = e & 63;
            const float4 wv = *(const float4*)(&W[(size_t)(k0 + kk) * N + colb + c]);
            Ws[kk][c + 0] = wv.x;
            Ws[kk][c + 1] = wv.y;
            Ws[kk][c + 2] = wv.z;
            Ws[kk][c + 3] = wv.w;
        }
        __syncthreads();
#pragma unroll
        for (int kk = 0; kk < 16; ++kk) {
            const float4 a = *(const float4*)&As[kk][ty * 4];
            const float4 w = *(const float4*)&Ws[kk][tx * 4];
            acc[0][0] += a.x * w.x; acc[0][1] += a.x * w.y; acc[0][2] += a.x * w.z; acc[0][3] += a.x * w.w;
            acc[1][0] += a.y * w.x; acc[1][1] += a.y * w.y; acc[1][2] += a.y * w.z; acc[1][3] += a.y * w.w;
            acc[2][0] += a.z * w.x; acc[2][1] += a.z * w.y; acc[2][2] += a.z * w.z; acc[2][3] += a.z * w.w;
            acc[3][0] += a.w * w.x; acc[3][1] += a.w * w.y; acc[3][2] += a.w * w.z; acc[3][3] += a.w * w.w;
        }
        __syncthreads();
    }

#pragma unroll
    for (int i = 0; i < 4; ++i) {
#pragma unroll
        for (int j = 0; j < 4; ++j) {
            const int orow = row0 + ty * 4 + i;
            const int ocol = colb + tx * 4 + j;
            const size_t oi = (size_t)orow * N + ocol;
            float v = acc[i][j];
            if constexpr (RES == 1) v += res[oi];
            C[oi] = v;
        }
    }
}

// ---------------------------------------------------------------------------
// Fused FFN-in: glu[M, 2048] = (A@W1[:, :2048]) * sigmoid(A@W1[:, 2048:])
// A[M, 1024], W1[1024, 4096]. 64x64 tile of glu per block.
// ---------------------------------------------------------------------------
__global__ __launch_bounds__(256) void gemm_glu_kernel(const float* __restrict__ A,
                                                       const float* __restrict__ W1,
                                                       float* __restrict__ glu) {
    __shared__ float As[16][68];
    __shared__ float Wl[16][68];
    __shared__ float Wr[16][68];

    const int tx = threadIdx.x;
    const int ty = threadIdx.y;
    const int tid = ty * 16 + tx;
    const int row0 = blockIdx.y * 64;
    const int colb = blockIdx.x * 64;
    const int K = DD;          // 1024
    const int N = 2 * DD;      // 2048 (glu width)
    const int ldw = 4 * DD;    // 4096 (W1 row stride)

    float accl[4][4] = {};
    float accr[4][4] = {};

    for (int k0 = 0; k0 < K; k0 += 16) {
        {
            int e = tid * 4;
            int r = e >> 4;
            int c = e & 15;
            const float4 av = *(const float4*)(&A[(size_t)(row0 + r) * K + k0 + c]);
            As[c + 0][r] = av.x;
            As[c + 1][r] = av.y;
            As[c + 2][r] = av.z;
            As[c + 3][r] = av.w;
        }
        {
            int e = tid * 4;
            int kk = e >> 6;
            int c = e & 63;
            const float4 wl = *(const float4*)(&W1[(size_t)(k0 + kk) * ldw + colb + c]);
            Wl[kk][c + 0] = wl.x; Wl[kk][c + 1] = wl.y; Wl[kk][c + 2] = wl.z; Wl[kk][c + 3] = wl.w;
            const float4 wr = *(const float4*)(&W1[(size_t)(k0 + kk) * ldw + N + colb + c]);
            Wr[kk][c + 0] = wr.x; Wr[kk][c + 1] = wr.y; Wr[kk][c + 2] = wr.z; Wr[kk][c + 3] = wr.w;
        }
        __syncthreads();
#pragma unroll
        for (int kk = 0; kk < 16; ++kk) {
            const float4 a = *(const float4*)&As[kk][ty * 4];
            const float4 l = *(const float4*)&Wl[kk][tx * 4];
            const float4 r = *(const float4*)&Wr[kk][tx * 4];
            accl[0][0] += a.x * l.x; accl[0][1] += a.x * l.y; accl[0][2] += a.x * l.z; accl[0][3] += a.x * l.w;
            accl[1][0] += a.y * l.x; accl[1][1] += a.y * l.y; accl[1][2] += a.y * l.z; accl[1][3] += a.y * l.w;
            accl[2][0] += a.z * l.x; accl[2][1] += a.z * l.y; accl[2][2] += a.z * l.z; accl[2][3] += a.z * l.w;
            accl[3][0] += a.w * l.x; accl[3][1] += a.w * l.y; accl[3][2] += a.w * l.z; accl[3][3] += a.w * l.w;
            accr[0][0] += a.x * r.x; accr[0][1] += a.x * r.y; accr[0][2] += a.x * r.z; accr[0][3] += a.x * r.w;
            accr[1][0] += a.y * r.x; accr[1][1] += a.y * r.y; accr[1][2] += a.y * r.z; accr[1][3] += a.y * r.w;
            accr[2][0] += a.z * r.x; accr[2][1] += a.z * r.y; accr[2][2] += a.z * r.z; accr[2][3] += a.z * r.w;
            accr[3][0] += a.w * r.x; accr[3][1] += a.w * r.y; accr[3][2] += a.w * r.z; accr[3][3] += a.w * r.w;
        }
        __syncthreads();
    }

#pragma unroll
    for (int i = 0; i < 4; ++i) {
#pragma unroll
        for (int j = 0; j < 4; ++j) {
            const int orow = row0 + ty * 4 + i;
            const int ocol = colb + tx * 4 + j;
            const float l = accl[i][j];
            const float r = accr[i][j];
            glu[(size_t)orow * N + ocol] = l * (1.0f / (1.0f + expf(-r)));
        }
    }
}

// ---------------------------------------------------------------------------
// Flash-style causal attention: one block per (b, h, q). Scores kept in LDS.
// q/k/v are fp32 [B*S, D] with head h in columns h*64..h*64+63.
// ---------------------------------------------------------------------------
__global__ __launch_bounds__(256) void flash_kernel(const float* __restrict__ q,
                                                    const float* __restrict__ k,
                                                    const float* __restrict__ v,
                                                    const int* __restrict__ mask,
                                                    float* __restrict__ out) {
    const int bid = blockIdx.x;
    const int qi = bid & (SS - 1);
    const int h = (bid >> 11) & (HH - 1);
    const int b = bid >> 15;
    const int tid = threadIdx.x;

    __shared__ float qv[DH];
    __shared__ float sc[SS];
    __shared__ float red[256];

    const size_t qoff = ((size_t)(b * SS + qi)) * DD + h * DH;
    if (tid < DH) qv[tid] = q[qoff + tid];
    __syncthreads();

    const int nk = qi + 1;  // causal

    // Phase 1: scores + local max
    float lmax = -INFINITY;
    for (int kk = tid; kk < nk; kk += 256) {
        const float* kp = k + ((size_t)(b * SS + kk)) * DD + h * DH;
        float s = 0.f;
#pragma unroll
        for (int d = 0; d < DH; d += 4) {
            const float4 kv4 = *(const float4*)(kp + d);
            s += qv[d] * kv4.x + qv[d + 1] * kv4.y + qv[d + 2] * kv4.z + qv[d + 3] * kv4.w;
        }
        s *= 0.125f;  // 1/sqrt(64)
        if (mask[b * SS + kk] == 0) s = -INFINITY;
        sc[kk] = s;
        lmax = fmaxf(lmax, s);
    }
    red[tid] = lmax;
    __syncthreads();
    for (int st = 128; st > 0; st >>= 1) {
        if (tid < st) red[tid] = fmaxf(red[tid], red[tid + st]);
        __syncthreads();
    }
    const float m = red[0];
    __syncthreads();

    // Phase 2: exp + sum
    float lsum = 0.f;
    for (int kk = tid; kk < nk; kk += 256) {
        const float e = expf(sc[kk] - m);
        sc[kk] = e;
        lsum += e;
    }
    red[tid] = lsum;
    __syncthreads();
    for (int st = 128; st > 0; st >>= 1) {
        if (tid < st) red[tid] += red[tid + st];
        __syncthreads();
    }
    const float denom = red[0];
    __syncthreads();

    // Phase 3: O[d] = sum_k p[k] * V[k][d]  (64 dims x 4 k-chunks)
    const int d = tid & 63;
    const int c = tid >> 6;
    float acc = 0.f;
    for (int kk = c; kk < nk; kk += 4)
        acc += sc[kk] * v[((size_t)(b * SS + kk)) * DD + h * DH + d];
    red[tid] = acc;
    __syncthreads();
    if (c == 0)
        out[qoff + d] = (red[d] + red[d + 64] + red[d + 128] + red[d + 192]) * (1.0f / denom);
}

// ---------------------------------------------------------------------------
// Launch. Workspace plan (64 MB peak):
//   bufA: ln1 -> attn -> ln2        (16 MB)
//   bufB: q   -> x1                 (16 MB)
//   bufC: k   -> glu[:, :  ]  \___  (32 MB spanning C+D, after k/v are dead)
//   bufD: v   -> glu[:, ...]  /
// ---------------------------------------------------------------------------
extern "C" void kernel_launch(void* const* d_in, const int* in_sizes, int n_in,
                              void* d_out, int out_size, void* d_ws, size_t ws_size,
                              hipStream_t stream) {
    const float* x  = (const float*)d_in[0];
    const int* mask = (const int*)d_in[1];
    const float* Wq = (const float*)d_in[2];
    const float* Wk = (const float*)d_in[3];
    const float* Wv = (const float*)d_in[4];
    const float* Wo = (const float*)d_in[5];
    const float* W1 = (const float*)d_in[6];
    const float* W2 = (const float*)d_in[7];
    const float* g1 = (const float*)d_in[8];
    const float* b1 = (const float*)d_in[9];
    const float* g2 = (const float*)d_in[10];
    const float* b2 = (const float*)d_in[11];

    const size_t M4 = (size_t)4 * 1024 * 1024;  // 4M floats = 16 MB
    float* bufA = (float*)d_ws;
    float* bufB = bufA + M4;
    float* bufC = bufB + M4;   // glu spans bufC..bufC+8M
    float* bufD = bufC + M4;

    const dim3 blk(16, 16);
    const dim3 g1024(1024 / 64, NTOK / 64);
    const dim3 g2048(2048 / 64, NTOK / 64);

    // 1. ln1 = LN(x) -> A
    ln_kernel<<<NTOK, 256, 0, stream>>>(x, g1, b1, bufA);

    // 2. q,k,v = ln1 @ {Wq,Wk,Wv} -> B, C, D
    gemm_kernel<0><<<g1024, blk, 0, stream>>>(bufA, Wq, nullptr, bufB, NTOK, DD, DD);
    gemm_kernel<0><<<g1024, blk, 0, stream>>>(bufA, Wk, nullptr, bufC, NTOK, DD, DD);
    gemm_kernel<0><<<g1024, blk, 0, stream>>>(bufA, Wv, nullptr, bufD, NTOK, DD, DD);

    // 3. attn = causal softmax(q k^T / 8) v -> A
    flash_kernel<<<BB * HH * SS, 256, 0, stream>>>(bufB, bufC, bufD, mask, bufA);

    // 4. x1 = x + attn @ Wo -> B
    gemm_kernel<1><<<g1024, blk, 0, stream>>>(bufA, Wo, x, bufB, NTOK, DD, DD);

    // 5. ln2 = LN(x1) -> A
    ln_kernel<<<NTOK, 256, 0, stream>>>(bufB, g2, b2, bufA);

    // 6. glu = (ln2 @ W1_left) * sigmoid(ln2 @ W1_right) -> C (8M floats)
    gemm_glu_kernel<<<g2048, blk, 0, stream>>>(bufA, W1, bufC);

    // 7. out = x1 + glu @ W2  (fp32 out)
    gemm_kernel<1><<<g1024, blk, 0, stream>>>(bufC, W2, bufB, (float*)d_out, NTOK, DD, 2 * DD);
}

// Round 3
// 1774.011 us; speedup vs baseline: 2.5413x; 2.5413x over previous
//
#include <hip/hip_runtime.h>
#include <hip/hip_bf16.h>
#include <math.h>

// Problem constants (B=2, S=2048, D=1024, H=16, DH=64)
#define BB 2
#define SS 2048
#define DD 1024
#define HH 16
#define DH 64
#define NTOK (BB * SS)   // 4096
#define LN_EPS 1e-5f

typedef __attribute__((ext_vector_type(8))) short bf16x8;   // 8 bf16 = 4 VGPRs
typedef __attribute__((ext_vector_type(4))) float f32x4;    // MFMA accumulator

static __device__ __forceinline__ float b2f(unsigned short u) {
    return __uint_as_float(((unsigned)u) << 16);
}
static __device__ __forceinline__ unsigned short f2bu(float f) {
    __hip_bfloat16 h = __float2bfloat16(f);
    return *(unsigned short*)&h;
}

// async 16B global -> LDS (direct-to-shared DMA). Dest is wave-uniform base +
// lane*16 — our staging mapping satisfies that by construction.
static __device__ __forceinline__ void async16(const void* g, void* l) {
    __builtin_amdgcn_global_load_lds((const __attribute__((address_space(1))) void*)g,
                                     (__attribute__((address_space(3))) void*)l, 16, 0, 0);
}

// ---------------------------------------------------------------------------
// Weight transpose+cast: Wt[n][k] = bf16(W[k][n]).  W fp32 [K][N].
// 32x32 tiles, coalesced both sides.
// ---------------------------------------------------------------------------
__global__ __launch_bounds__(256) void transpose_cast(const float* __restrict__ W,
                                                      __hip_bfloat16* __restrict__ Wt,
                                                      int K, int N) {
    __shared__ float t[32][33];
    const int n0 = blockIdx.x * 32, k0 = blockIdx.y * 32;
    const int tx = threadIdx.x & 31, ty = threadIdx.x >> 5;  // ty 0..7
#pragma unroll
    for (int i = 0; i < 4; ++i)
        t[ty + 8 * i][tx] = W[(size_t)(k0 + ty + 8 * i) * N + n0 + tx];
    __syncthreads();
#pragma unroll
    for (int i = 0; i < 4; ++i)
        Wt[(size_t)(n0 + ty + 8 * i) * K + k0 + tx] = __float2bfloat16(t[tx][ty + 8 * i]);
}

// ---------------------------------------------------------------------------
// LayerNorm fp32 -> bf16 (feeds MFMA GEMMs). One block per row, D=1024.
// ---------------------------------------------------------------------------
__global__ __launch_bounds__(256) void ln_kernel(const float* __restrict__ x,
                                                 const float* __restrict__ gamma,
                                                 const float* __restrict__ beta,
                                                 __hip_bfloat16* __restrict__ out) {
    const int row = blockIdx.x;
    const int tid = threadIdx.x;
    __shared__ float red[256];

    const float* xp = x + (size_t)row * DD;
    float vals[4];
    float s = 0.f;
#pragma unroll
    for (int i = 0; i < 4; ++i) {
        float v = xp[tid + i * 256];
        vals[i] = v;
        s += v;
    }
    red[tid] = s;
    __syncthreads();
    for (int st = 128; st > 0; st >>= 1) {
        if (tid < st) red[tid] += red[tid + st];
        __syncthreads();
    }
    const float mu = red[0] * (1.0f / DD);
    __syncthreads();
    float sq = 0.f;
#pragma unroll
    for (int i = 0; i < 4; ++i) {
        float d = vals[i] - mu;
        sq += d * d;
    }
    red[tid] = sq;
    __syncthreads();
    for (int st = 128; st > 0; st >>= 1) {
        if (tid < st) red[tid] += red[tid + st];
        __syncthreads();
    }
    const float rinv = rsqrtf(red[0] * (1.0f / DD) + LN_EPS);

    __hip_bfloat16* op = out + (size_t)row * DD;
#pragma unroll
    for (int i = 0; i < 4; ++i) {
        int j = tid + i * 256;
        op[j] = __float2bfloat16(gamma[j] * ((vals[i] - mu) * rinv) + beta[j]);
    }
}

// ---------------------------------------------------------------------------
// MFMA bf16 GEMM (m97 structure): C[M,N] = A[M,K] @ Bt[N,K]^T
// 128x128 block tile, 4 waves (2x2 of 64x64), BK=64, global_load_lds staging.
// RES: 0 none, 1 add fp32 res[oi].
// EPI: 0 fp32 out, 1 bf16 out, 2 glu: out_bf16 = res_bf16[oi] * sigmoid(acc)
// ---------------------------------------------------------------------------
template <int RES, int EPI>
__global__ __launch_bounds__(256) void mfma_gemm(const __hip_bfloat16* __restrict__ A,
                                                 const __hip_bfloat16* __restrict__ Bt,
                                                 const void* __restrict__ res,
                                                 void* __restrict__ out,
                                                 int M, int N, int K) {
    __shared__ short As[128 * 64];
    __shared__ short Bs[128 * 64];
    const int tid = threadIdx.x;
    const int lane = tid & 63;
    const int wave = tid >> 6;
    const int row0 = blockIdx.y * 128;
    const int col0 = blockIdx.x * 128;
    const int wr = (wave >> 1) * 64;
    const int wc = (wave & 1) * 64;
    const int l15 = lane & 15;
    const int lk8 = (lane >> 4) * 8;   // A[m][k]: m=lane&15, k=quad*8+j  (HW-verified layout)

    f32x4 acc[4][4] = {};

    for (int k0 = 0; k0 < K; k0 += 64) {
        // stage A,B tiles 128x64 bf16: 4 rounds x 256 threads x 8 elems (16 B)
#pragma unroll
        for (int r = 0; r < 4; ++r) {
            const int e = (r * 256 + tid) * 8;
            const int ar = e >> 6, ac = e & 63;
            async16(&A[(size_t)(row0 + ar) * K + k0 + ac], &As[e]);
            async16(&Bt[(size_t)(col0 + ar) * K + k0 + ac], &Bs[e]);
        }
        __syncthreads();
#pragma unroll
        for (int kk = 0; kk < 2; ++kk) {
            bf16x8 af[4], bfr[4];
#pragma unroll
            for (int i = 0; i < 4; ++i)
                af[i] = *(const bf16x8*)&As[(wr + i * 16 + l15) * 64 + kk * 32 + lk8];
#pragma unroll
            for (int j = 0; j < 4; ++j)
                bfr[j] = *(const bf16x8*)&Bs[(wc + j * 16 + l15) * 64 + kk * 32 + lk8];
#pragma unroll
            for (int i = 0; i < 4; ++i)
#pragma unroll
                for (int j = 0; j < 4; ++j)
                    acc[i][j] = __builtin_amdgcn_mfma_f32_16x16x32_bf16(af[i], bfr[j], acc[i][j], 0, 0, 0);
        }
        __syncthreads();
    }

    // Epilogue. C/D: col = lane&15, row = quad*4 + reg (HW-verified).
    const int r4 = (lane >> 4) * 4;
#pragma unroll
    for (int i = 0; i < 4; ++i) {
#pragma unroll
        for (int j = 0; j < 4; ++j) {
#pragma unroll
            for (int rg = 0; rg < 4; ++rg) {
                const int orow = row0 + wr + i * 16 + r4 + rg;
                const int ocol = col0 + wc + j * 16 + l15;
                const size_t oi = (size_t)orow * N + ocol;
                float v = acc[i][j][rg];
                if constexpr (RES == 1) v += ((const float*)res)[oi];
                if constexpr (EPI == 0) ((float*)out)[oi] = v;
                if constexpr (EPI == 1) ((__hip_bfloat16*)out)[oi] = __float2bfloat16(v);
                if constexpr (EPI == 2) {
                    const float l = b2f(((const unsigned short*)res)[oi]);
                    ((__hip_bfloat16*)out)[oi] =
                        __float2bfloat16(l * (1.f / (1.f + __expf(-v))));
                }
            }
        }
    }
}

// ---------------------------------------------------------------------------
// Register-resident flash attention. 128 threads/block; lane owns one query
// (q-row 64 fp32 regs + O-acc 64 regs, online softmax). K/V staged to LDS in
// 32-row chunks as fp32; inner reads are wave-broadcast (conflict-free).
// qkv bf16 [B*S][3072] (q|k|v each 1024 wide); out bf16 [B*S][1024].
// ---------------------------------------------------------------------------
#define QT 128
__global__ __launch_bounds__(128, 2) void flash_kernel(const __hip_bfloat16* __restrict__ qkv,
                                                       const int* __restrict__ mask,
                                                       __hip_bfloat16* __restrict__ attnb) {
    const int bid = blockIdx.x;        // b*256 + h*16 + qt
    const int qt = bid & 15;
    const int h = (bid >> 4) & 15;
    const int b = bid >> 8;
    const int tid = threadIdx.x;
    const int q = qt * QT + tid;

    __shared__ float Ks[32][64];
    __shared__ float Vs[32][64];
    __shared__ float Ms[32];

    float qv[64], o[64];
    {
        const unsigned short* qp =
            (const unsigned short*)qkv + (size_t)(b * SS + q) * 3072 + h * 64;
#pragma unroll
        for (int i = 0; i < 16; ++i) {
            const ushort4 u = ((const ushort4*)qp)[i];
            qv[4 * i + 0] = b2f(u.x);
            qv[4 * i + 1] = b2f(u.y);
            qv[4 * i + 2] = b2f(u.z);
            qv[4 * i + 3] = b2f(u.w);
        }
    }
#pragma unroll
    for (int j = 0; j < 64; ++j) o[j] = 0.f;
    float m = -INFINITY, l = 0.f;

    const int kend = qt * QT + QT;
    for (int kb = 0; kb < kend; kb += 32) {
        // stage K,V (32x64 bf16 -> fp32) + mask
        {
            const int r = tid >> 2, c = (tid & 3) * 16;
            const unsigned short* kp =
                (const unsigned short*)qkv + (size_t)(b * SS + kb + r) * 3072 + 1024 + h * 64 + c;
            const unsigned short* vp = kp + 1024;
#pragma unroll
            for (int i = 0; i < 4; ++i) {
                const ushort4 u = *(const ushort4*)(kp + 4 * i);
                Ks[r][c + 4 * i + 0] = b2f(u.x);
                Ks[r][c + 4 * i + 1] = b2f(u.y);
                Ks[r][c + 4 * i + 2] = b2f(u.z);
                Ks[r][c + 4 * i + 3] = b2f(u.w);
                const ushort4 w = *(const ushort4*)(vp + 4 * i);
                Vs[r][c + 4 * i + 0] = b2f(w.x);
                Vs[r][c + 4 * i + 1] = b2f(w.y);
                Vs[r][c + 4 * i + 2] = b2f(w.z);
                Vs[r][c + 4 * i + 3] = b2f(w.w);
            }
            if (tid < 32) Ms[tid] = mask[b * SS + kb + tid] ? 1.f : 0.f;
        }
        __syncthreads();

        int kmax = q - kb + 1;               // causal: k <= q
        if (kmax > 32) kmax = 32;
        for (int kk = 0; kk < kmax; ++kk) {
            if (Ms[kk] != 0.f) {
                float s = 0.f;
#pragma unroll
                for (int j4 = 0; j4 < 16; ++j4) {
                    const float4 kv = *(const float4*)&Ks[kk][4 * j4];
                    s += qv[4 * j4 + 0] * kv.x + qv[4 * j4 + 1] * kv.y +
                         qv[4 * j4 + 2] * kv.z + qv[4 * j4 + 3] * kv.w;
                }
                s *= 0.125f;  // 1/sqrt(64)
                if (s > m) {
                    const float sc = __expf(m - s);  // m=-inf first time -> 0
                    l *= sc;
#pragma unroll
                    for (int j = 0; j < 64; ++j) o[j] *= sc;
                    m = s;
                }
                const float p = __expf(s - m);
                l += p;
#pragma unroll
                for (int j4 = 0; j4 < 16; ++j4) {
                    const float4 vv = *(const float4*)&Vs[kk][4 * j4];
                    o[4 * j4 + 0] += p * vv.x;
                    o[4 * j4 + 1] += p * vv.y;
                    o[4 * j4 + 2] += p * vv.z;
                    o[4 * j4 + 3] += p * vv.w;
                }
            }
        }
        __syncthreads();
    }

    const float inv = 1.f / l;
    unsigned short* op = (unsigned short*)attnb + (size_t)(b * SS + q) * 1024 + h * 64;
#pragma unroll
    for (int j4 = 0; j4 < 16; ++j4) {
        ushort4 u;
        u.x = f2bu(o[4 * j4 + 0] * inv);
        u.y = f2bu(o[4 * j4 + 1] * inv);
        u.z = f2bu(o[4 * j4 + 2] * inv);
        u.w = f2bu(o[4 * j4 + 3] * inv);
        *(ushort4*)(op + 4 * j4) = u;
    }
}

// ---------------------------------------------------------------------------
// Launch. Workspace plan (60 MB peak), offsets in bytes:
//   [0,6M)   Wqkv_t bf16 [3072][1024]   (live all)
//   [6,8M)   Wo_t   bf16 [1024][1024]
//   [8,16M)  W1_t   bf16 [4096][1024]
//   [16,20M) W2_t   bf16 [1024][2048]
//   [20,28M) lnb    bf16 (ln1 then ln2)
//   [28,52M) qkvb   bf16 [4096][3072]   -> dead after flash
//   [28,44M) x1     fp32                (reuses qkvb head)
//   [52,60M) attnb  bf16                -> dead after Wo gemm
//   [44,60M) leftb/glub bf16 [4096][2048] (reuses qkvb tail + attnb)
// ---------------------------------------------------------------------------
extern "C" void kernel_launch(void* const* d_in, const int* in_sizes, int n_in,
                              void* d_out, int out_size, void* d_ws, size_t ws_size,
                              hipStream_t stream) {
    const float* x  = (const float*)d_in[0];
    const int* mask = (const int*)d_in[1];
    const float* Wq = (const float*)d_in[2];
    const float* Wk = (const float*)d_in[3];
    const float* Wv = (const float*)d_in[4];
    const float* Wo = (const float*)d_in[5];
    const float* W1 = (const float*)d_in[6];
    const float* W2 = (const float*)d_in[7];
    const float* g1 = (const float*)d_in[8];
    const float* b1 = (const float*)d_in[9];
    const float* g2 = (const float*)d_in[10];
    const float* b2 = (const float*)d_in[11];

    const size_t MB = 1024 * 1024;
    uint8_t* ws = (uint8_t*)d_ws;
    __hip_bfloat16* wqkvt = (__hip_bfloat16*)(ws);
    __hip_bfloat16* wot   = (__hip_bfloat16*)(ws + 6 * MB);
    __hip_bfloat16* w1t   = (__hip_bfloat16*)(ws + 8 * MB);
    __hip_bfloat16* w2t   = (__hip_bfloat16*)(ws + 16 * MB);
    __hip_bfloat16* lnb   = (__hip_bfloat16*)(ws + 20 * MB);
    __hip_bfloat16* qkvb  = (__hip_bfloat16*)(ws + 28 * MB);
    float*          x1    = (float*)(ws + 28 * MB);
    __hip_bfloat16* leftb = (__hip_bfloat16*)(ws + 44 * MB);
    __hip_bfloat16* attnb = (__hip_bfloat16*)(ws + 52 * MB);

    // 0. weight cast+transpose (bf16, B^T layout)
    transpose_cast<<<dim3(32, 32), 256, 0, stream>>>(Wq, wqkvt + 0 * 1024 * 1024, 1024, 1024);
    transpose_cast<<<dim3(32, 32), 256, 0, stream>>>(Wk, wqkvt + 1 * 1024 * 1024, 1024, 1024);
    transpose_cast<<<dim3(32, 32), 256, 0, stream>>>(Wv, wqkvt + 2 * 1024 * 1024, 1024, 1024);
    transpose_cast<<<dim3(32, 32), 256, 0, stream>>>(Wo, wot, 1024, 1024);
    transpose_cast<<<dim3(128, 32), 256, 0, stream>>>(W1, w1t, 1024, 4096);
    transpose_cast<<<dim3(32, 64), 256, 0, stream>>>(W2, w2t, 2048, 1024);

    // 1. ln1 = LN(x) -> lnb (bf16)
    ln_kernel<<<NTOK, 256, 0, stream>>>(x, g1, b1, lnb);

    // 2. qkv = ln1 @ [Wq|Wk|Wv] -> qkvb (bf16, N=3072)
    mfma_gemm<0, 1><<<dim3(24, 32), 256, 0, stream>>>(lnb, wqkvt, nullptr, qkvb, NTOK, 3072, 1024);

    // 3. flash attention -> attnb (bf16)
    flash_kernel<<<BB * HH * (SS / QT), QT, 0, stream>>>(qkvb, mask, attnb);

    // 4. x1 = x + attn @ Wo -> x1 (fp32)
    mfma_gemm<1, 0><<<dim3(8, 32), 256, 0, stream>>>(attnb, wot, x, x1, NTOK, 1024, 1024);

    // 5. ln2 = LN(x1) -> lnb (bf16)
    ln_kernel<<<NTOK, 256, 0, stream>>>(x1, g2, b2, lnb);

    // 6. left = ln2 @ W1[:, :2048] -> leftb (bf16)
    mfma_gemm<0, 1><<<dim3(16, 32), 256, 0, stream>>>(lnb, w1t, nullptr, leftb, NTOK, 2048, 1024);

    // 7. glu = leftb * sigmoid(ln2 @ W1[:, 2048:]) -> in place over leftb
    mfma_gemm<0, 2><<<dim3(16, 32), 256, 0, stream>>>(lnb, w1t + 2048 * 1024, leftb, leftb,
                                                      NTOK, 2048, 1024);

    // 8. out = x1 + glu @ W2 -> d_out (fp32)
    mfma_gemm<1, 0><<<dim3(8, 32), 256, 0, stream>>>(leftb, w2t, x1, (float*)d_out,
                                                     NTOK, 1024, 2048);
}

// Round 4
// 451.390 us; speedup vs baseline: 9.9876x; 3.9301x over previous
//
#include <hip/hip_runtime.h>
#include <hip/hip_bf16.h>
#include <math.h>

// Problem constants (B=2, S=2048, D=1024, H=16, DH=64)
#define BB 2
#define SS 2048
#define DD 1024
#define HH 16
#define DH 64
#define NTOK (BB * SS)   // 4096
#define LN_EPS 1e-5f
#define BIGNEG -1e30f

typedef __attribute__((ext_vector_type(8))) short bf16x8;   // 8 bf16 = 4 VGPRs
typedef __attribute__((ext_vector_type(4))) float f32x4;    // MFMA accumulator

static __device__ __forceinline__ float b2f(unsigned short u) {
    return __uint_as_float(((unsigned)u) << 16);
}
static __device__ __forceinline__ unsigned short f2bu(float f) {
    __hip_bfloat16 h = __float2bfloat16(f);
    return *(unsigned short*)&h;
}

// async 16B global -> LDS. LDS dest must be wave-uniform base + lane*16.
static __device__ __forceinline__ void async16(const void* g, void* l) {
    __builtin_amdgcn_global_load_lds((const __attribute__((address_space(1))) void*)g,
                                     (__attribute__((address_space(3))) void*)l, 16, 0, 0);
}

// ---------------------------------------------------------------------------
// Weight transpose+cast: Wt[n][k] = bf16(W[k][n]).  W fp32 [K][N].
// ---------------------------------------------------------------------------
__global__ __launch_bounds__(256) void transpose_cast(const float* __restrict__ W,
                                                      __hip_bfloat16* __restrict__ Wt,
                                                      int K, int N) {
    __shared__ float t[32][33];
    const int n0 = blockIdx.x * 32, k0 = blockIdx.y * 32;
    const int tx = threadIdx.x & 31, ty = threadIdx.x >> 5;  // ty 0..7
#pragma unroll
    for (int i = 0; i < 4; ++i)
        t[ty + 8 * i][tx] = W[(size_t)(k0 + ty + 8 * i) * N + n0 + tx];
    __syncthreads();
#pragma unroll
    for (int i = 0; i < 4; ++i)
        Wt[(size_t)(n0 + ty + 8 * i) * K + k0 + tx] = __float2bfloat16(t[tx][ty + 8 * i]);
}

// ---------------------------------------------------------------------------
// LayerNorm fp32 -> bf16. One block per row, D=1024.
// ---------------------------------------------------------------------------
__global__ __launch_bounds__(256) void ln_kernel(const float* __restrict__ x,
                                                 const float* __restrict__ gamma,
                                                 const float* __restrict__ beta,
                                                 __hip_bfloat16* __restrict__ out) {
    const int row = blockIdx.x;
    const int tid = threadIdx.x;
    __shared__ float red[256];

    const float* xp = x + (size_t)row * DD;
    float vals[4];
    float s = 0.f;
#pragma unroll
    for (int i = 0; i < 4; ++i) {
        float v = xp[tid + i * 256];
        vals[i] = v;
        s += v;
    }
    red[tid] = s;
    __syncthreads();
    for (int st = 128; st > 0; st >>= 1) {
        if (tid < st) red[tid] += red[tid + st];
        __syncthreads();
    }
    const float mu = red[0] * (1.0f / DD);
    __syncthreads();
    float sq = 0.f;
#pragma unroll
    for (int i = 0; i < 4; ++i) {
        float d = vals[i] - mu;
        sq += d * d;
    }
    red[tid] = sq;
    __syncthreads();
    for (int st = 128; st > 0; st >>= 1) {
        if (tid < st) red[tid] += red[tid + st];
        __syncthreads();
    }
    const float rinv = rsqrtf(red[0] * (1.0f / DD) + LN_EPS);

    __hip_bfloat16* op = out + (size_t)row * DD;
#pragma unroll
    for (int i = 0; i < 4; ++i) {
        int j = tid + i * 256;
        op[j] = __float2bfloat16(gamma[j] * ((vals[i] - mu) * rinv) + beta[j]);
    }
}

// ---------------------------------------------------------------------------
// MFMA bf16 GEMM (m97 structure): C[M,N] = A[M,K] @ Bt[N,K]^T
// 128x128 tile, 4 waves, BK=64, global_load_lds staging.
// RES: 0 none, 1 add fp32 res[oi].
// EPI: 0 fp32 out, 1 bf16 out, 2 glu: out_bf16 = res_bf16[oi] * sigmoid(acc)
// ---------------------------------------------------------------------------
template <int RES, int EPI>
__global__ __launch_bounds__(256) void mfma_gemm(const __hip_bfloat16* __restrict__ A,
                                                 const __hip_bfloat16* __restrict__ Bt,
                                                 const void* __restrict__ res,
                                                 void* __restrict__ out,
                                                 int M, int N, int K) {
    __shared__ short As[128 * 64];
    __shared__ short Bs[128 * 64];
    const int tid = threadIdx.x;
    const int lane = tid & 63;
    const int wave = tid >> 6;
    const int row0 = blockIdx.y * 128;
    const int col0 = blockIdx.x * 128;
    const int wr = (wave >> 1) * 64;
    const int wc = (wave & 1) * 64;
    const int l15 = lane & 15;
    const int lk8 = (lane >> 4) * 8;

    f32x4 acc[4][4] = {};

    for (int k0 = 0; k0 < K; k0 += 64) {
#pragma unroll
        for (int r = 0; r < 4; ++r) {
            const int e = (r * 256 + tid) * 8;
            const int ar = e >> 6, ac = e & 63;
            async16(&A[(size_t)(row0 + ar) * K + k0 + ac], &As[e]);
            async16(&Bt[(size_t)(col0 + ar) * K + k0 + ac], &Bs[e]);
        }
        __syncthreads();
#pragma unroll
        for (int kk = 0; kk < 2; ++kk) {
            bf16x8 af[4], bfr[4];
#pragma unroll
            for (int i = 0; i < 4; ++i)
                af[i] = *(const bf16x8*)&As[(wr + i * 16 + l15) * 64 + kk * 32 + lk8];
#pragma unroll
            for (int j = 0; j < 4; ++j)
                bfr[j] = *(const bf16x8*)&Bs[(wc + j * 16 + l15) * 64 + kk * 32 + lk8];
#pragma unroll
            for (int i = 0; i < 4; ++i)
#pragma unroll
                for (int j = 0; j < 4; ++j)
                    acc[i][j] = __builtin_amdgcn_mfma_f32_16x16x32_bf16(af[i], bfr[j], acc[i][j], 0, 0, 0);
        }
        __syncthreads();
    }

    const int r4 = (lane >> 4) * 4;
#pragma unroll
    for (int i = 0; i < 4; ++i) {
#pragma unroll
        for (int j = 0; j < 4; ++j) {
#pragma unroll
            for (int rg = 0; rg < 4; ++rg) {
                const int orow = row0 + wr + i * 16 + r4 + rg;
                const int ocol = col0 + wc + j * 16 + l15;
                const size_t oi = (size_t)orow * N + ocol;
                float v = acc[i][j][rg];
                if constexpr (RES == 1) v += ((const float*)res)[oi];
                if constexpr (EPI == 0) ((float*)out)[oi] = v;
                if constexpr (EPI == 1) ((__hip_bfloat16*)out)[oi] = __float2bfloat16(v);
                if constexpr (EPI == 2) {
                    const float l = b2f(((const unsigned short*)res)[oi]);
                    ((__hip_bfloat16*)out)[oi] =
                        __float2bfloat16(l * (1.f / (1.f + __expf(-v))));
                }
            }
        }
    }
}

// ---------------------------------------------------------------------------
// MFMA flash attention. Block = 256 threads (4 waves), 128 queries/block
// (wave owns 32 = two 16-row tiles). K loop in 64-key chunks staged in LDS:
// Ks [key][dim] (global_load_lds, stride 64), Vt [dim][key] (transposed,
// stride 72 = conflict-free), P per-wave [q][key] stride 72 (LDS round-trip
// from MFMA C-layout to A-layout). Online softmax per (tile,reg) row with
// 16-lane shfl_xor reductions.
// qkv bf16 [B*S][3072] (q|k|v); out bf16 [B*S][1024].
// ---------------------------------------------------------------------------
#define VSTR 72
__global__ __launch_bounds__(256) void flash_mfma(const __hip_bfloat16* __restrict__ qkv_,
                                                  const int* __restrict__ mask,
                                                  __hip_bfloat16* __restrict__ attnb) {
    const unsigned short* qkv = (const unsigned short*)qkv_;
    __shared__ __align__(16) short Ks[64 * 64];
    __shared__ __align__(16) short Vt[64 * VSTR];
    __shared__ __align__(16) short Ps[4][32 * VSTR];
    __shared__ float Ms[64];

    const int tid = threadIdx.x;
    const int lane = tid & 63;
    const int wave = tid >> 6;
    const int l15 = lane & 15;
    const int quad = lane >> 4;
    const int qt = blockIdx.x & 15;
    const int h = (blockIdx.x >> 4) & 15;
    const int b = blockIdx.x >> 8;
    const int q0 = qt * 128 + wave * 32;   // wave's first query

    // Q fragments (A-layout): m=lane&15 -> query, k=quad*8+j -> dim
    bf16x8 aq[2][2];
#pragma unroll
    for (int t = 0; t < 2; ++t)
#pragma unroll
        for (int ks = 0; ks < 2; ++ks)
            aq[t][ks] = *(const bf16x8*)(qkv + (size_t)(b * SS + q0 + t * 16 + l15) * 3072 +
                                         h * 64 + ks * 32 + quad * 8);

    f32x4 O[2][4];
    float m_r[2][4], l_r[2][4];
#pragma unroll
    for (int t = 0; t < 2; ++t)
#pragma unroll
        for (int i = 0; i < 4; ++i) {
            O[t][i] = (f32x4){0.f, 0.f, 0.f, 0.f};
            m_r[t][i] = BIGNEG;
            l_r[t][i] = 0.f;
        }

    const int kend = qt * 128 + 128;
    for (int kb = 0; kb < kend; kb += 64) {
        __syncthreads();  // protect prev-iter LDS reads before overwrite
        // stage K chunk: 64x64 bf16 via global_load_lds (2 rounds x 256 x 16B)
#pragma unroll
        for (int r = 0; r < 2; ++r) {
            const int e8 = (r * 256 + tid) * 8;
            const int key = e8 >> 6, dim = e8 & 63;
            async16(qkv + (size_t)(b * SS + kb + key) * 3072 + 1024 + h * 64 + dim, &Ks[e8]);
        }
        // stage V transposed: Vt[dim][key], stride 72
        {
            const int key = lane;
            const int d0 = wave * 16;
            const unsigned short* vp =
                qkv + (size_t)(b * SS + kb + key) * 3072 + 2048 + h * 64 + d0;
#pragma unroll
            for (int i = 0; i < 4; ++i) {
                const ushort4 u = *(const ushort4*)(vp + 4 * i);
                Vt[(d0 + 4 * i + 0) * VSTR + key] = (short)u.x;
                Vt[(d0 + 4 * i + 1) * VSTR + key] = (short)u.y;
                Vt[(d0 + 4 * i + 2) * VSTR + key] = (short)u.z;
                Vt[(d0 + 4 * i + 3) * VSTR + key] = (short)u.w;
            }
        }
        if (tid < 64) Ms[tid] = mask[b * SS + kb + tid] ? 1.f : 0.f;
        __syncthreads();

        if (kb <= q0 + 31) {   // this wave has live queries in this chunk
            // ---- S = Q K^T (C-layout: col=key-in-tile, row=query-in-tile)
            f32x4 S[2][4];
#pragma unroll
            for (int kt = 0; kt < 4; ++kt) {
                const bf16x8 bk0 = *(const bf16x8*)&Ks[(kt * 16 + l15) * 64 + quad * 8];
                const bf16x8 bk1 = *(const bf16x8*)&Ks[(kt * 16 + l15) * 64 + 32 + quad * 8];
#pragma unroll
                for (int t = 0; t < 2; ++t) {
                    f32x4 z = {0.f, 0.f, 0.f, 0.f};
                    z = __builtin_amdgcn_mfma_f32_16x16x32_bf16(aq[t][0], bk0, z, 0, 0, 0);
                    S[t][kt] = __builtin_amdgcn_mfma_f32_16x16x32_bf16(aq[t][1], bk1, z, 0, 0, 0);
                }
            }
            // ---- causal + attention mask + scale
            float msk[4];
#pragma unroll
            for (int kt = 0; kt < 4; ++kt) msk[kt] = Ms[kt * 16 + l15];
#pragma unroll
            for (int t = 0; t < 2; ++t) {
                const int qrow = q0 + t * 16 + quad * 4;
#pragma unroll
                for (int kt = 0; kt < 4; ++kt) {
                    const int key = kb + kt * 16 + l15;
#pragma unroll
                    for (int rg = 0; rg < 4; ++rg) {
                        const bool valid = (key <= qrow + rg) && (msk[kt] != 0.f);
                        S[t][kt][rg] = valid ? S[t][kt][rg] * 0.125f : BIGNEG;
                    }
                }
            }
            // ---- online softmax (row reduce across the 16 lanes of the quad)
            float alpha[2][4];
#pragma unroll
            for (int t = 0; t < 2; ++t)
#pragma unroll
                for (int rg = 0; rg < 4; ++rg) {
                    float v = fmaxf(fmaxf(S[t][0][rg], S[t][1][rg]),
                                    fmaxf(S[t][2][rg], S[t][3][rg]));
                    v = fmaxf(v, __shfl_xor(v, 1));
                    v = fmaxf(v, __shfl_xor(v, 2));
                    v = fmaxf(v, __shfl_xor(v, 4));
                    v = fmaxf(v, __shfl_xor(v, 8));
                    const float mn = fmaxf(m_r[t][rg], v);
                    const float al = __expf(m_r[t][rg] - mn);
                    m_r[t][rg] = mn;
                    alpha[t][rg] = al;
                    l_r[t][rg] *= al;
                }
#pragma unroll
            for (int t = 0; t < 2; ++t)
#pragma unroll
                for (int kt = 0; kt < 4; ++kt)
#pragma unroll
                    for (int rg = 0; rg < 4; ++rg)
                        S[t][kt][rg] = __expf(S[t][kt][rg] - m_r[t][rg]);
#pragma unroll
            for (int t = 0; t < 2; ++t)
#pragma unroll
                for (int rg = 0; rg < 4; ++rg) {
                    float v = S[t][0][rg] + S[t][1][rg] + S[t][2][rg] + S[t][3][rg];
                    v += __shfl_xor(v, 1);
                    v += __shfl_xor(v, 2);
                    v += __shfl_xor(v, 4);
                    v += __shfl_xor(v, 8);
                    l_r[t][rg] += v;
                }
            // ---- rescale O
#pragma unroll
            for (int t = 0; t < 2; ++t)
#pragma unroll
                for (int nt = 0; nt < 4; ++nt)
#pragma unroll
                    for (int rg = 0; rg < 4; ++rg)
                        O[t][nt][rg] *= alpha[t][rg];
            // ---- P: C-layout regs -> per-wave LDS -> A-layout frags
            short* Pw = &Ps[wave][0];
#pragma unroll
            for (int t = 0; t < 2; ++t)
#pragma unroll
                for (int kt = 0; kt < 4; ++kt)
#pragma unroll
                    for (int rg = 0; rg < 4; ++rg)
                        Pw[(t * 16 + quad * 4 + rg) * VSTR + kt * 16 + l15] =
                            (short)f2bu(S[t][kt][rg]);
            asm volatile("s_waitcnt lgkmcnt(0)" ::: "memory");
            // ---- O += P V
#pragma unroll
            for (int t = 0; t < 2; ++t) {
                const bf16x8 ap0 = *(const bf16x8*)&Pw[(t * 16 + l15) * VSTR + quad * 8];
                const bf16x8 ap1 = *(const bf16x8*)&Pw[(t * 16 + l15) * VSTR + 32 + quad * 8];
#pragma unroll
                for (int nt = 0; nt < 4; ++nt) {
                    const bf16x8 bv0 = *(const bf16x8*)&Vt[(nt * 16 + l15) * VSTR + quad * 8];
                    const bf16x8 bv1 = *(const bf16x8*)&Vt[(nt * 16 + l15) * VSTR + 32 + quad * 8];
                    O[t][nt] = __builtin_amdgcn_mfma_f32_16x16x32_bf16(ap0, bv0, O[t][nt], 0, 0, 0);
                    O[t][nt] = __builtin_amdgcn_mfma_f32_16x16x32_bf16(ap1, bv1, O[t][nt], 0, 0, 0);
                }
            }
        }
    }

    // epilogue: O /= l, write bf16
#pragma unroll
    for (int t = 0; t < 2; ++t)
#pragma unroll
        for (int rg = 0; rg < 4; ++rg) {
            const int q = q0 + t * 16 + quad * 4 + rg;
            const float inv = 1.f / l_r[t][rg];
            unsigned short* op = (unsigned short*)attnb + (size_t)(b * SS + q) * 1024 + h * 64;
#pragma unroll
            for (int nt = 0; nt < 4; ++nt)
                op[nt * 16 + l15] = f2bu(O[t][nt][rg] * inv);
        }
}

// ---------------------------------------------------------------------------
// Launch. Workspace plan (60 MB peak), offsets in bytes:
//   [0,6M)   Wqkv_t bf16 [3072][1024]
//   [6,8M)   Wo_t   bf16 [1024][1024]
//   [8,16M)  W1_t   bf16 [4096][1024]
//   [16,20M) W2_t   bf16 [1024][2048]
//   [20,28M) lnb    bf16 (ln1 then ln2)
//   [28,52M) qkvb   bf16 [4096][3072]   -> dead after flash
//   [28,44M) x1     fp32                (reuses qkvb head)
//   [52,60M) attnb  bf16                -> dead after Wo gemm
//   [44,60M) leftb/glub bf16 [4096][2048]
// ---------------------------------------------------------------------------
extern "C" void kernel_launch(void* const* d_in, const int* in_sizes, int n_in,
                              void* d_out, int out_size, void* d_ws, size_t ws_size,
                              hipStream_t stream) {
    const float* x  = (const float*)d_in[0];
    const int* mask = (const int*)d_in[1];
    const float* Wq = (const float*)d_in[2];
    const float* Wk = (const float*)d_in[3];
    const float* Wv = (const float*)d_in[4];
    const float* Wo = (const float*)d_in[5];
    const float* W1 = (const float*)d_in[6];
    const float* W2 = (const float*)d_in[7];
    const float* g1 = (const float*)d_in[8];
    const float* b1 = (const float*)d_in[9];
    const float* g2 = (const float*)d_in[10];
    const float* b2 = (const float*)d_in[11];

    const size_t MB = 1024 * 1024;
    uint8_t* ws = (uint8_t*)d_ws;
    __hip_bfloat16* wqkvt = (__hip_bfloat16*)(ws);
    __hip_bfloat16* wot   = (__hip_bfloat16*)(ws + 6 * MB);
    __hip_bfloat16* w1t   = (__hip_bfloat16*)(ws + 8 * MB);
    __hip_bfloat16* w2t   = (__hip_bfloat16*)(ws + 16 * MB);
    __hip_bfloat16* lnb   = (__hip_bfloat16*)(ws + 20 * MB);
    __hip_bfloat16* qkvb  = (__hip_bfloat16*)(ws + 28 * MB);
    float*          x1    = (float*)(ws + 28 * MB);
    __hip_bfloat16* leftb = (__hip_bfloat16*)(ws + 44 * MB);
    __hip_bfloat16* attnb = (__hip_bfloat16*)(ws + 52 * MB);

    // 0. weight cast+transpose (bf16, B^T layout)
    transpose_cast<<<dim3(32, 32), 256, 0, stream>>>(Wq, wqkvt + 0 * 1024 * 1024, 1024, 1024);
    transpose_cast<<<dim3(32, 32), 256, 0, stream>>>(Wk, wqkvt + 1 * 1024 * 1024, 1024, 1024);
    transpose_cast<<<dim3(32, 32), 256, 0, stream>>>(Wv, wqkvt + 2 * 1024 * 1024, 1024, 1024);
    transpose_cast<<<dim3(32, 32), 256, 0, stream>>>(Wo, wot, 1024, 1024);
    transpose_cast<<<dim3(128, 32), 256, 0, stream>>>(W1, w1t, 1024, 4096);
    transpose_cast<<<dim3(32, 64), 256, 0, stream>>>(W2, w2t, 2048, 1024);

    // 1. ln1 = LN(x) -> lnb
    ln_kernel<<<NTOK, 256, 0, stream>>>(x, g1, b1, lnb);

    // 2. qkv = ln1 @ [Wq|Wk|Wv] -> qkvb (N=3072)
    mfma_gemm<0, 1><<<dim3(24, 32), 256, 0, stream>>>(lnb, wqkvt, nullptr, qkvb, NTOK, 3072, 1024);

    // 3. MFMA flash attention -> attnb
    flash_mfma<<<BB * HH * 16, 256, 0, stream>>>(qkvb, mask, attnb);

    // 4. x1 = x + attn @ Wo -> x1 (fp32)
    mfma_gemm<1, 0><<<dim3(8, 32), 256, 0, stream>>>(attnb, wot, x, x1, NTOK, 1024, 1024);

    // 5. ln2 = LN(x1) -> lnb
    ln_kernel<<<NTOK, 256, 0, stream>>>(x1, g2, b2, lnb);

    // 6. left = ln2 @ W1[:, :2048] -> leftb
    mfma_gemm<0, 1><<<dim3(16, 32), 256, 0, stream>>>(lnb, w1t, nullptr, leftb, NTOK, 2048, 1024);

    // 7. glu = leftb * sigmoid(ln2 @ W1[:, 2048:]) -> in place over leftb
    mfma_gemm<0, 2><<<dim3(16, 32), 256, 0, stream>>>(lnb, w1t + 2048 * 1024, leftb, leftb,
                                                      NTOK, 2048, 1024);

    // 8. out = x1 + glu @ W2 -> d_out (fp32)
    mfma_gemm<1, 0><<<dim3(8, 32), 256, 0, stream>>>(leftb, w2t, x1, (float*)d_out,
                                                     NTOK, 1024, 2048);
}